// Round 17
// baseline (842.539 us; speedup 1.0000x reference)
//
#include <hip/hip_runtime.h>
#include <hip/hip_bf16.h>

typedef __attribute__((ext_vector_type(8))) short short8;
typedef __attribute__((ext_vector_type(4))) float f32x4;
typedef unsigned long long u64;

#define GLOAD16(g, l) __builtin_amdgcn_global_load_lds( \
    (const __attribute__((address_space(1))) void*)(g), \
    (__attribute__((address_space(3))) void*)(l), 16, 0, 0)

#define F18 262144.0f            // 2^18 pass1 fixed-point scale
#define F18I (1.0f / 262144.0f)
#define F20 1048576.0f           // 2^20 pass2 fixed-point scale
#define F20I (1.0f / 1048576.0f)

__device__ __forceinline__ ushort f2bf(float v)
{
  __hip_bfloat16 b = __float2bfloat16(v);
  return *reinterpret_cast<ushort*>(&b);
}

// bijective XCD-chunk swizzle (m204): each of 8 XCDs gets a contiguous chunk
__device__ __forceinline__ int xcd_swz(int bid, int nwg)
{
  int q = nwg >> 3, rr = nwg & 7;
  int xcd = bid & 7, idx = bid >> 3;
  return (xcd < rr) ? xcd * (q + 1) + idx : rr * (q + 1) + (xcd - rr) * q + idx;
}

// ---------------------------------------------------------------------------
// Threefry2x32 (JAX partitionable semantics) + erfinv (XLA f32 polynomial)
// ---------------------------------------------------------------------------
#define TF_ROUND(r) { x0 += x1; x1 = ((x1<<(r))|(x1>>(32-(r)))); x1 ^= x0; }

__device__ __forceinline__ void tf2x32(unsigned k0, unsigned k1, unsigned x0, unsigned x1,
                                       unsigned &o0, unsigned &o1)
{
  unsigned ks2 = k0 ^ k1 ^ 0x1BD11BDAu;
  x0 += k0; x1 += k1;
  TF_ROUND(13) TF_ROUND(15) TF_ROUND(26) TF_ROUND(6)
  x0 += k1;  x1 += ks2 + 1u;
  TF_ROUND(17) TF_ROUND(29) TF_ROUND(16) TF_ROUND(24)
  x0 += ks2; x1 += k0 + 2u;
  TF_ROUND(13) TF_ROUND(15) TF_ROUND(26) TF_ROUND(6)
  x0 += k0;  x1 += k1 + 3u;
  TF_ROUND(17) TF_ROUND(29) TF_ROUND(16) TF_ROUND(24)
  x0 += k1;  x1 += ks2 + 4u;
  TF_ROUND(13) TF_ROUND(15) TF_ROUND(26) TF_ROUND(6)
  x0 += ks2; x1 += k0 + 5u;
  o0 = x0; o1 = x1;
}

__device__ __forceinline__ float erfinv_f(float x)
{
  float w = -log1pf(-x * x);
  float p;
  if (w < 5.0f) {
    w -= 2.5f;
    p = 2.81022636e-08f;
    p = fmaf(p, w, 3.43273939e-07f);
    p = fmaf(p, w, -3.5233877e-06f);
    p = fmaf(p, w, -4.39150654e-06f);
    p = fmaf(p, w, 0.00021858087f);
    p = fmaf(p, w, -0.00125372503f);
    p = fmaf(p, w, -0.00417768164f);
    p = fmaf(p, w, 0.246640727f);
    p = fmaf(p, w, 1.50140941f);
  } else {
    w = sqrtf(w) - 3.0f;
    p = -0.000200214257f;
    p = fmaf(p, w, 0.000100950558f);
    p = fmaf(p, w, 0.00134934322f);
    p = fmaf(p, w, -0.00367342844f);
    p = fmaf(p, w, 0.00573950773f);
    p = fmaf(p, w, -0.0076224613f);
    p = fmaf(p, w, 0.00943887047f);
    p = fmaf(p, w, 1.00167406f);
    p = fmaf(p, w, 2.83297682f);
  }
  return p * x;
}

__device__ __forceinline__ float rng_normal(unsigned b)
{
  float f = __uint_as_float((b >> 9) | 0x3f800000u) - 1.0f;  // [0,1)
  const float lo = -0.99999994f;
  float u = fmaxf(lo, f * 2.0f + lo);
  return 1.41421356f * erfinv_f(u);
}

__device__ __forceinline__ float softplusf(float x) { return log1pf(expf(x)); }

// ---------------------------------------------------------------------------
// DDE pass1 — packed u64 atomics [count:12][y:26][x:26] @2^18.
// P1h's count field doubles as the h-histogram for the edge sort.
// ---------------------------------------------------------------------------
__global__ void dde_pass1(const int* __restrict__ h, const int* __restrict__ t,
                          const float* __restrict__ topic,
                          u64* __restrict__ P1t, u64* __restrict__ P1h, int E)
{
  int e = blockIdx.x * blockDim.x + threadIdx.x;
  if (e >= E) return;
  int hh = h[e], tt = t[e];
  float2 th = *reinterpret_cast<const float2*>(&topic[hh * 2]);
  float2 tv = *reinterpret_cast<const float2*>(&topic[tt * 2]);
  u64 vt = (1ULL << 52) | ((u64)(unsigned)(th.y * F18 + 0.5f) << 26) | (unsigned)(th.x * F18 + 0.5f);
  u64 vh = (1ULL << 52) | ((u64)(unsigned)(tv.y * F18 + 0.5f) << 26) | (unsigned)(tv.x * F18 + 0.5f);
  atomicAdd(&P1t[tt], vt);
  atomicAdd(&P1h[hh], vh);
}

__global__ void dde_norm1(const u64* __restrict__ P1t, const u64* __restrict__ P1h,
                          float* __restrict__ f1n, float* __restrict__ g1n, int N)
{
  int n = blockIdx.x * blockDim.x + threadIdx.x;
  if (n >= N) return;
  u64 pt = P1t[n];
  float st = F18I / fmaxf((float)(unsigned)(pt >> 52), 1.0f);
  f1n[n*2+0] = (float)(unsigned)(pt & 0x3FFFFFFu) * st;
  f1n[n*2+1] = (float)(unsigned)((pt >> 26) & 0x3FFFFFFu) * st;
  u64 ph = P1h[n];
  float sh = F18I / fmaxf((float)(unsigned)(ph >> 52), 1.0f);
  g1n[n*2+0] = (float)(unsigned)(ph & 0x3FFFFFFu) * sh;
  g1n[n*2+1] = (float)(unsigned)((ph >> 26) & 0x3FFFFFFu) * sh;
}

// ---------------------------------------------------------------------------
// FUSED: DDE pass2 + counting-sort scatter — 2 atomics/edge (R15-proven).
// G2_h packs [count:12][y:26][x:26] @2^20; returned count -> scatter pos.
// ---------------------------------------------------------------------------
__global__ void dde_pass2_scatter(const int* __restrict__ h, const int* __restrict__ t,
                                  const int* __restrict__ r,
                                  const float* __restrict__ f1n, const float* __restrict__ g1n,
                                  u64* __restrict__ F2_t, u64* __restrict__ G2_h,
                                  const int* __restrict__ cbase, int4* __restrict__ se, int E)
{
  int e = blockIdx.x * blockDim.x + threadIdx.x;
  if (e >= E) return;
  int hh = h[e], tt = t[e];
  float2 fv = *reinterpret_cast<const float2*>(&f1n[hh * 2]);
  float2 gv = *reinterpret_cast<const float2*>(&g1n[tt * 2]);
  atomicAdd(&F2_t[tt], ((u64)(unsigned)(fv.y * F20 + 0.5f) << 32) | (unsigned)(fv.x * F20 + 0.5f));
  u64 old = atomicAdd(&G2_h[hh],
      (1ULL << 52) | ((u64)(unsigned)(gv.y * F20 + 0.5f) << 26) | (unsigned)(gv.x * F20 + 0.5f));
  int pos = cbase[hh] + (int)(unsigned)(old >> 52);
  se[pos] = make_int4(hh, tt, r[e], e);
}

// ---------------------------------------------------------------------------
// Edge counting sort scans: counts come from P1h[52:].
// ---------------------------------------------------------------------------
__global__ void scan1(const u64* __restrict__ P1h, int* __restrict__ bsum, int N)
{
  __shared__ int sh[256];
  int b = blockIdx.x, t = threadIdx.x;
  int base = b * 1024 + t * 4;
  int s = 0;
  #pragma unroll
  for (int i = 0; i < 4; ++i) if (base + i < N) s += (int)(unsigned)(P1h[base + i] >> 52);
  sh[t] = s;
  __syncthreads();
  for (int off = 128; off >= 1; off >>= 1) {
    if (t < off) sh[t] += sh[t + off];
    __syncthreads();
  }
  if (t == 0) bsum[b] = sh[0];
}

__global__ void scan2(const int* __restrict__ bsum, int* __restrict__ bscan, int NB)
{
  __shared__ int sh[256];
  int t = threadIdx.x;
  sh[t] = (t < NB) ? bsum[t] : 0;
  __syncthreads();
  if (t == 0) {
    int run = 0;
    for (int i = 0; i < NB; ++i) { int v = sh[i]; sh[i] = run; run += v; }
  }
  __syncthreads();
  if (t < NB) bscan[t] = sh[t];
}

__global__ void scan3(const u64* __restrict__ P1h, const int* __restrict__ bscan,
                      int* __restrict__ cursor, int N)
{
  __shared__ int sh[256];
  int b = blockIdx.x, t = threadIdx.x;
  int base = b * 1024 + t * 4;
  int c[4];
  #pragma unroll
  for (int i = 0; i < 4; ++i) c[i] = (base + i < N) ? (int)(unsigned)(P1h[base + i] >> 52) : 0;
  int mysum = c[0] + c[1] + c[2] + c[3];
  sh[t] = mysum;
  __syncthreads();
  for (int off = 1; off < 256; off <<= 1) {
    int u = (t >= off) ? sh[t - off] : 0;
    __syncthreads();
    sh[t] += u;
    __syncthreads();
  }
  int excl = sh[t] - mysum + bscan[b];
  #pragma unroll
  for (int i = 0; i < 4; ++i) {
    if (base + i < N) cursor[base + i] = excl;
    excl += c[i];
  }
}

// ---------------------------------------------------------------------------
// Entity feature matrix h_e : [N][288] bf16 — vectorized, norm2 fused.
// ---------------------------------------------------------------------------
__global__ void build_he(const float* __restrict__ emb, const float* __restrict__ nte,
                         const float* __restrict__ topic,
                         const float* __restrict__ f1, const float* __restrict__ g1,
                         const u64* __restrict__ F2_t, const u64* __restrict__ G2_h,
                         const u64* __restrict__ P1t, const u64* __restrict__ P1h,
                         __hip_bfloat16* __restrict__ He, int N, int nText)
{
  int idx = blockIdx.x * blockDim.x + threadIdx.x;
  if (idx >= N * 36) return;
  int n = idx / 36, j8 = idx - n * 36;
  ushort r[8];
  if (j8 < 32) {
    const float* src = (n < nText) ? &emb[(size_t)n * 256 + j8 * 8] : &nte[j8 * 8];
    float4 v0 = *reinterpret_cast<const float4*>(src);
    float4 v1 = *reinterpret_cast<const float4*>(src + 4);
    const float vv[8] = {v0.x, v0.y, v0.z, v0.w, v1.x, v1.y, v1.z, v1.w};
    #pragma unroll
    for (int i = 0; i < 8; ++i) r[i] = f2bf(vv[i]);
  } else if (j8 == 32) {
    float2 tp = *reinterpret_cast<const float2*>(&topic[n*2]);
    float2 a  = *reinterpret_cast<const float2*>(&f1[n*2]);
    float st = F20I / fmaxf((float)(unsigned)(P1t[n] >> 52), 1.0f);
    u64 f = F2_t[n];
    float f2x = (float)(unsigned)(f & 0xFFFFFFFFu) * st;
    float f2y = (float)(unsigned)(f >> 32) * st;
    float2 cq = *reinterpret_cast<const float2*>(&g1[n*2]);
    const float vv[8] = {tp.x, tp.y, a.x, a.y, f2x, f2y, cq.x, cq.y};
    #pragma unroll
    for (int i = 0; i < 8; ++i) r[i] = f2bf(vv[i]);
  } else if (j8 == 33) {
    float sh = F20I / fmaxf((float)(unsigned)(P1h[n] >> 52), 1.0f);
    u64 g = G2_h[n];
    r[0] = f2bf((float)(unsigned)(g & 0x3FFFFFFu) * sh);
    r[1] = f2bf((float)(unsigned)((g >> 26) & 0x3FFFFFFu) * sh);
    #pragma unroll
    for (int i = 2; i < 8; ++i) r[i] = 0;
  } else {
    #pragma unroll
    for (int i = 0; i < 8; ++i) r[i] = 0;
  }
  *reinterpret_cast<short8*>((ushort*)He + (size_t)n * 288 + j8 * 8) =
      *reinterpret_cast<const short8*>(r);
}

// rel -> bf16 (one-time)
__global__ void rel_cvt(const float* __restrict__ rel, __hip_bfloat16* __restrict__ relb, int n)
{
  int i = blockIdx.x * blockDim.x + threadIdx.x;
  if (i < n) relb[i] = __float2bfloat16(rel[i]);
}

// ---------------------------------------------------------------------------
// Bayesian weight sampling (JAX threefry, partitionable) + packing (verified)
// ---------------------------------------------------------------------------
__global__ void sample_kernel(int s,
                              const float* __restrict__ w1_mu, const float* __restrict__ w1_rho,
                              const float* __restrict__ b1_mu, const float* __restrict__ b1_rho,
                              const float* __restrict__ w2_mu, const float* __restrict__ w2_rho,
                              const float* __restrict__ b2_mu, const float* __restrict__ b2_rho,
                              float* __restrict__ W1s, float* __restrict__ b1s,
                              float* __restrict__ w2s, float* __restrict__ b2s,
                              __hip_bfloat16* __restrict__ As, __hip_bfloat16* __restrict__ Asr)
{
  const int W1N = 267264;   // 256*1044
  int tid = blockIdx.x * blockDim.x + threadIdx.x;
  unsigned F0, F1;
  tf2x32(0u, 42u, 0u, (unsigned)s, F0, F1);   // fold_in(key(42), s)

  if (tid < W1N) {
    unsigned k0, k1; tf2x32(F0, F1, 0u, 0u, k0, k1);              // sk0
    unsigned o0, o1; tf2x32(k0, k1, 0u, (unsigned)tid, o0, o1);
    float w = fmaf(rng_normal(o0 ^ o1), softplusf(w1_rho[tid]), w1_mu[tid]);
    W1s[tid] = w;
    int m = tid / 1044, j = tid - m * 1044;
    if (j >= 256 && j < 522)      As[m * 288 + (j - 256)]         = __float2bfloat16(w);
    else if (j >= 522 && j < 778) Asr[m * 256 + (j - 522)]        = __float2bfloat16(w);
    else if (j >= 778)            As[(256 + m) * 288 + (j - 778)] = __float2bfloat16(w);
  } else if (tid < W1N + 256) {
    int m = tid - W1N;
    unsigned k0, k1; tf2x32(F0, F1, 0u, 1u, k0, k1);              // sk1
    unsigned o0, o1; tf2x32(k0, k1, 0u, (unsigned)m, o0, o1);
    b1s[m] = fmaf(rng_normal(o0 ^ o1), softplusf(b1_rho[m]), b1_mu[m]);
  } else if (tid < W1N + 512) {
    int m = tid - (W1N + 256);
    unsigned k0, k1; tf2x32(F0, F1, 0u, 2u, k0, k1);              // sk2
    unsigned o0, o1; tf2x32(k0, k1, 0u, (unsigned)m, o0, o1);
    w2s[m] = fmaf(rng_normal(o0 ^ o1), softplusf(w2_rho[m]), w2_mu[m]);
  } else if (tid == W1N + 512) {
    unsigned k0, k1; tf2x32(F0, F1, 0u, 3u, k0, k1);              // sk3
    unsigned o0, o1; tf2x32(k0, k1, 0u, 0u, o0, o1);
    b2s[0] = fmaf(rng_normal(o0 ^ o1), softplusf(b2_rho[0]), b2_mu[0]);
  }
}

// c[k] = b1s[k] + sum_j W1s[k][j] * q[j]  — one wave per k, coalesced (f32)
__global__ void c_kernel(const float* __restrict__ W1s, const float* __restrict__ b1s,
                         const float* __restrict__ q, float* __restrict__ cvec)
{
  int k = blockIdx.x * 4 + (threadIdx.x >> 6);
  int lane = threadIdx.x & 63;
  float4 v  = *reinterpret_cast<const float4*>(&W1s[(size_t)k * 1044 + lane * 4]);
  float4 qv = *reinterpret_cast<const float4*>(&q[lane * 4]);
  float acc = v.x*qv.x + v.y*qv.y + v.z*qv.z + v.w*qv.w;
  #pragma unroll
  for (int off = 32; off >= 1; off >>= 1) acc += __shfl_down(acc, off, 64);
  if (lane == 0) cvec[k] = acc + b1s[k];
}

// ---------------------------------------------------------------------------
// Arc[r][k] = cvec[k] + sum_j rel[r][j]*W1[k][522+j] via MFMA. f32 out.
// ---------------------------------------------------------------------------
__global__ __launch_bounds__(256) void ar_mfma(const __hip_bfloat16* __restrict__ relb_,
                                               const __hip_bfloat16* __restrict__ Asr_,
                                               const float* __restrict__ cvec,
                                               float* __restrict__ Arc, int NRr)
{
  const int lane = threadIdx.x & 63;
  const int wid  = threadIdx.x >> 6;
  const int wr = wid >> 1, wc = wid & 1;
  const int r0 = blockIdx.y * 128 + wr * 64;
  const int k0 = blockIdx.x * 128 + wc * 64;
  const int lr = lane & 15, lk = (lane >> 4) * 8;
  const short* A = (const short*)relb_;
  const short* B = (const short*)Asr_;

  const short* pa[4];
  const short* pb[4];
  #pragma unroll
  for (int i = 0; i < 4; ++i) {
    int rr = r0 + i * 16 + lr; if (rr >= NRr) rr = NRr - 1;
    pa[i] = A + (size_t)rr * 256 + lk;
    pb[i] = B + (size_t)(k0 + i * 16 + lr) * 256 + lk;
  }
  f32x4 acc[4][4] = {};
  #pragma unroll
  for (int ks = 0; ks < 8; ++ks) {
    short8 a[4], b[4];
    #pragma unroll
    for (int i = 0; i < 4; ++i) a[i] = *reinterpret_cast<const short8*>(pa[i] + ks * 32);
    #pragma unroll
    for (int j = 0; j < 4; ++j) b[j] = *reinterpret_cast<const short8*>(pb[j] + ks * 32);
    #pragma unroll
    for (int i = 0; i < 4; ++i)
      #pragma unroll
      for (int j = 0; j < 4; ++j)
        acc[i][j] = __builtin_amdgcn_mfma_f32_16x16x32_bf16(a[i], b[j], acc[i][j], 0, 0, 0);
  }
  const int rg = (lane >> 4) * 4;
  #pragma unroll
  for (int i = 0; i < 4; ++i) {
    #pragma unroll
    for (int r_ = 0; r_ < 4; ++r_) {
      int r = r0 + i * 16 + rg + r_;
      if (r < NRr) {
        #pragma unroll
        for (int j = 0; j < 4; ++j) {
          int k = k0 + j * 16 + lr;
          Arc[(size_t)r * 256 + k] = acc[i][j][r_] + cvec[k];
        }
      }
    }
  }
}

// ---------------------------------------------------------------------------
// MFMA GEMM v4 (verified): 256n x 128m tile, BK=32, 8 waves, dbuf LDS via
// global_load_lds w16, 4-way-max XOR swizzle, XCD-chunk-swizzled 1-D grid.
// ---------------------------------------------------------------------------
__global__ __launch_bounds__(512) void gemm_mfma(const __hip_bfloat16* __restrict__ Heb,
                                                 const __hip_bfloat16* __restrict__ Asb,
                                                 __hip_bfloat16* __restrict__ U, int nEnt)
{
  __shared__ short lA[2][8192];
  __shared__ short lB[2][4096];

  const int tid  = threadIdx.x;
  const int lane = tid & 63;
  const int wid  = tid >> 6;
  const int wr   = wid >> 1;
  const int wc   = wid & 1;
  const int swzb = xcd_swz(blockIdx.x, gridDim.x);
  const int m0   = (swzb & 3) * 128;
  const int n0   = (swzb >> 2) * 256;
  const short* He = (const short*)Heb;
  const short* As = (const short*)Asb;

  const int lr  = lane & 15;
  const int kb  = (lane >> 4) * 16;
  const int swz = (lane & 3) << 4;

  const int g0row = tid >> 2, g0c = tid & 3;
  const int g1row = g0row + 128;
  const int maxA = nEnt - n0 - 1;
  const int a0r = g0row <= maxA ? g0row : maxA;
  const int a1r = g1row <= maxA ? g1row : maxA;
  const size_t aoff0 = (size_t)a0r * 288 + (g0c ^ (g0row & 3)) * 8;
  const size_t aoff1 = (size_t)a1r * 288 + (g0c ^ (g1row & 3)) * 8;
  const size_t boff0 = (size_t)g0row * 288 + (g0c ^ (g0row & 3)) * 8;
  const short* gA = He + (size_t)n0 * 288;
  const short* gB = As + (size_t)m0 * 288;

  #define STAGE(buf, k0)                                              \
    { GLOAD16(gA + (k0) + aoff0, (char*)lA[buf] + tid * 16);          \
      GLOAD16(gA + (k0) + aoff1, (char*)lA[buf] + tid * 16 + 8192);   \
      GLOAD16(gB + (k0) + boff0, (char*)lB[buf] + tid * 16); }

  f32x4 acc[4][4] = {};

  STAGE(0, 0)
  __syncthreads();

  #pragma unroll 1
  for (int ks = 0; ks < 9; ++ks) {
    const int cur = ks & 1;
    if (ks < 8) STAGE(cur ^ 1, (ks + 1) * 32)

    short8 a[4], b[4];
    #pragma unroll
    for (int i = 0; i < 4; ++i) {
      int rowA = wr * 64 + i * 16 + lr;
      a[i] = *reinterpret_cast<const short8*>((const char*)lA[cur] + rowA * 64 + (kb ^ swz));
      int rowB = wc * 64 + i * 16 + lr;
      b[i] = *reinterpret_cast<const short8*>((const char*)lB[cur] + rowB * 64 + (kb ^ swz));
    }
    #pragma unroll
    for (int i = 0; i < 4; ++i)
      #pragma unroll
      for (int j = 0; j < 4; ++j)
        acc[i][j] = __builtin_amdgcn_mfma_f32_16x16x32_bf16(a[i], b[j], acc[i][j], 0, 0, 0);

    __syncthreads();
  }
  #undef STAGE

  const int rg = (lane >> 4) * 4;
  #pragma unroll
  for (int i = 0; i < 4; ++i) {
    #pragma unroll
    for (int r = 0; r < 4; ++r) {
      int n = n0 + wr * 64 + i * 16 + rg + r;
      if (n < nEnt) {
        #pragma unroll
        for (int j = 0; j < 4; ++j)
          U[(size_t)n * 512 + m0 + wc * 64 + j * 16 + lr] = __float2bfloat16(acc[i][j][r]);
      }
    }
  }
}

// ---------------------------------------------------------------------------
// Edge pass v4: ns (1 or 2) samples per launch, each with its OWN w2/b2.
// Per edge: one se load + one reduce + one acc op serve both samples.
// mode 0: acc=v, 1: acc+=v, 2: out[orig]=(acc+v)*0.2
// ---------------------------------------------------------------------------
#define EITER 4
__global__ __launch_bounds__(256) void edge2_kernel(const int4* __restrict__ se,
                                                    const __hip_bfloat16* __restrict__ U0,
                                                    const __hip_bfloat16* __restrict__ U1,
                                                    const float* __restrict__ Arc0,
                                                    const float* __restrict__ Arc1,
                                                    const float* __restrict__ w2s0,
                                                    const float* __restrict__ w2s1,
                                                    const float* __restrict__ b2s0,
                                                    const float* __restrict__ b2s1,
                                                    float* __restrict__ acc,
                                                    float* __restrict__ out, int E,
                                                    int ns, int mode)
{
  int blk = xcd_swz(blockIdx.x, gridDim.x);
  int g = threadIdx.x >> 5;
  int l = threadIdx.x & 31;
  int base = blk * (8 * EITER) + g * EITER;
  const ushort* Ub0 = (const ushort*)U0;
  const ushort* Ub1 = (const ushort*)U1;

  float4 wa0 = *reinterpret_cast<const float4*>(&w2s0[l * 8]);
  float4 wa1 = *reinterpret_cast<const float4*>(&w2s0[l * 8 + 4]);
  const float ww0[8] = {wa0.x, wa0.y, wa0.z, wa0.w, wa1.x, wa1.y, wa1.z, wa1.w};
  float4 wb0 = *reinterpret_cast<const float4*>(&w2s1[l * 8]);
  float4 wb1 = *reinterpret_cast<const float4*>(&w2s1[l * 8 + 4]);
  const float ww1[8] = {wb0.x, wb0.y, wb0.z, wb0.w, wb1.x, wb1.y, wb1.z, wb1.w};
  float b2sum = b2s0[0] + ((ns == 2) ? b2s1[0] : 0.0f);

  #pragma unroll 1
  for (int it = 0; it < EITER; ++it) {
    int e = base + it;
    if (e >= E) break;
    int4 ed = se[e];
    size_t ho = (size_t)ed.x * 512 + l * 8;
    size_t to = (size_t)ed.y * 512 + 256 + l * 8;
    size_t ao = (size_t)ed.z * 256 + l * 8;

    float sum = 0.0f;

    {
      uint4 uhv = *reinterpret_cast<const uint4*>(Ub0 + ho);
      uint4 utv = *reinterpret_cast<const uint4*>(Ub0 + to);
      float4 a0 = *reinterpret_cast<const float4*>(&Arc0[ao]);
      float4 a1 = *reinterpret_cast<const float4*>(&Arc0[ao + 4]);
      float uh[8], ut[8];
      uh[0] = __uint_as_float(uhv.x << 16); uh[1] = __uint_as_float(uhv.x & 0xFFFF0000u);
      uh[2] = __uint_as_float(uhv.y << 16); uh[3] = __uint_as_float(uhv.y & 0xFFFF0000u);
      uh[4] = __uint_as_float(uhv.z << 16); uh[5] = __uint_as_float(uhv.z & 0xFFFF0000u);
      uh[6] = __uint_as_float(uhv.w << 16); uh[7] = __uint_as_float(uhv.w & 0xFFFF0000u);
      ut[0] = __uint_as_float(utv.x << 16); ut[1] = __uint_as_float(utv.x & 0xFFFF0000u);
      ut[2] = __uint_as_float(utv.y << 16); ut[3] = __uint_as_float(utv.y & 0xFFFF0000u);
      ut[4] = __uint_as_float(utv.z << 16); ut[5] = __uint_as_float(utv.z & 0xFFFF0000u);
      ut[6] = __uint_as_float(utv.w << 16); ut[7] = __uint_as_float(utv.w & 0xFFFF0000u);
      const float aa[8] = {a0.x, a0.y, a0.z, a0.w, a1.x, a1.y, a1.z, a1.w};
      #pragma unroll
      for (int i = 0; i < 8; ++i)
        sum += ww0[i] * fmaxf(aa[i] + uh[i] + ut[i], 0.0f);
    }

    if (ns == 2) {
      uint4 uhv = *reinterpret_cast<const uint4*>(Ub1 + ho);
      uint4 utv = *reinterpret_cast<const uint4*>(Ub1 + to);
      float4 a0 = *reinterpret_cast<const float4*>(&Arc1[ao]);
      float4 a1 = *reinterpret_cast<const float4*>(&Arc1[ao + 4]);
      float uh[8], ut[8];
      uh[0] = __uint_as_float(uhv.x << 16); uh[1] = __uint_as_float(uhv.x & 0xFFFF0000u);
      uh[2] = __uint_as_float(uhv.y << 16); uh[3] = __uint_as_float(uhv.y & 0xFFFF0000u);
      uh[4] = __uint_as_float(uhv.z << 16); uh[5] = __uint_as_float(uhv.z & 0xFFFF0000u);
      uh[6] = __uint_as_float(uhv.w << 16); uh[7] = __uint_as_float(uhv.w & 0xFFFF0000u);
      ut[0] = __uint_as_float(utv.x << 16); ut[1] = __uint_as_float(utv.x & 0xFFFF0000u);
      ut[2] = __uint_as_float(utv.y << 16); ut[3] = __uint_as_float(utv.y & 0xFFFF0000u);
      ut[4] = __uint_as_float(utv.z << 16); ut[5] = __uint_as_float(utv.z & 0xFFFF0000u);
      ut[6] = __uint_as_float(utv.w << 16); ut[7] = __uint_as_float(utv.w & 0xFFFF0000u);
      const float aa[8] = {a0.x, a0.y, a0.z, a0.w, a1.x, a1.y, a1.z, a1.w};
      #pragma unroll
      for (int i = 0; i < 8; ++i)
        sum += ww1[i] * fmaxf(aa[i] + uh[i] + ut[i], 0.0f);
    }

    #pragma unroll
    for (int off = 16; off >= 1; off >>= 1) sum += __shfl_down(sum, off, 32);

    if (l == 0) {
      float v = sum + b2sum;
      if (mode == 0)      acc[e] = v;
      else if (mode == 1) acc[e] += v;
      else                out[ed.w] = (acc[e] + v) * 0.2f;
    }
  }
}

// ---------------------------------------------------------------------------
// Host launcher
// ---------------------------------------------------------------------------
extern "C" void kernel_launch(void* const* d_in, const int* in_sizes, int n_in,
                              void* d_out, int out_size, void* d_ws, size_t ws_size,
                              hipStream_t stream)
{
  const int*   h_id  = (const int*)  d_in[0];
  const int*   r_id  = (const int*)  d_in[1];
  const int*   t_id  = (const int*)  d_in[2];
  const float* q     = (const float*)d_in[3];
  const float* emb   = (const float*)d_in[4];
  const float* rel   = (const float*)d_in[6];
  const float* topic = (const float*)d_in[7];
  const float* nte   = (const float*)d_in[8];
  const float* w1_mu = (const float*)d_in[9];
  const float* w1_rho= (const float*)d_in[10];
  const float* b1_mu = (const float*)d_in[11];
  const float* b1_rho= (const float*)d_in[12];
  const float* w2_mu = (const float*)d_in[13];
  const float* w2_rho= (const float*)d_in[14];
  const float* b2_mu = (const float*)d_in[15];
  const float* b2_rho= (const float*)d_in[16];

  const int E     = in_sizes[0];
  const int nText = in_sizes[4] / 256;
  const int N     = in_sizes[7] / 2;
  const int NR    = in_sizes[6] / 256;
  float* out = (float*)d_out;

  char* ws = (char*)d_ws;
  size_t off = 0;
  auto alloc = [&](size_t bytes) -> void* {
    void* p = (void*)(ws + off);
    off += (bytes + 255) & ~(size_t)255;
    return p;
  };
  __hip_bfloat16* He  = (__hip_bfloat16*)alloc((size_t)N * 288 * 2);
  __hip_bfloat16* U0  = (__hip_bfloat16*)alloc((size_t)N * 512 * 2);
  __hip_bfloat16* U1  = (__hip_bfloat16*)alloc((size_t)N * 512 * 2);
  __hip_bfloat16* Asr = (__hip_bfloat16*)alloc(256 * 256 * 2);
  __hip_bfloat16* relb= (__hip_bfloat16*)alloc((size_t)NR * 256 * 2);
  float* Arc0 = (float*)alloc((size_t)NR * 256 * 4);
  float* Arc1 = (float*)alloc((size_t)NR * 256 * 4);
  float* W1s  = (float*)alloc(267264 * 4);
  float* b1s  = (float*)alloc(256 * 4);
  float* w2s0 = (float*)alloc(256 * 4);
  float* w2s1 = (float*)alloc(256 * 4);
  float* b2s0 = (float*)alloc(64 * 4);
  float* b2s1 = (float*)alloc(64 * 4);
  float* cvec = (float*)alloc(256 * 4);
  float* f1n  = (float*)alloc((size_t)2 * N * 4);
  float* g1n  = (float*)alloc((size_t)2 * N * 4);
  float* eacc = (float*)alloc((size_t)E * 4);
  int4*  se   = (int4*)alloc((size_t)E * 16);
  const int NB = (N + 1023) / 1024;
  int* cursor = (int*)alloc((size_t)NB * 1024 * 4);
  int* bsum   = (int*)alloc(256 * 4);
  int* bscan  = (int*)alloc(256 * 4);
  // zero-init region: As pad cols + packed DDE accumulators
  __hip_bfloat16* As = (__hip_bfloat16*)alloc(512 * 288 * 2);
  u64* P1t  = (u64*)alloc((size_t)N * 8);
  u64* P1h  = (u64*)alloc((size_t)N * 8);
  u64* F2_t = (u64*)alloc((size_t)N * 8);
  u64* G2_h = (u64*)alloc((size_t)N * 8);

  size_t zero_bytes = (size_t)((char*)(G2_h + N) - (char*)As);
  hipMemsetAsync(As, 0, zero_bytes, stream);

  int eb = (E + 255) / 256;
  int nb = (N + 255) / 256;
  dde_pass1<<<eb, 256, 0, stream>>>(h_id, t_id, topic, P1t, P1h, E);
  dde_norm1<<<nb, 256, 0, stream>>>(P1t, P1h, f1n, g1n, N);

  // counting-sort base offsets (from P1h high bits), then fused pass2+scatter
  scan1<<<NB, 256, 0, stream>>>(P1h, bsum, N);
  scan2<<<1, 256, 0, stream>>>(bsum, bscan, NB);
  scan3<<<NB, 256, 0, stream>>>(P1h, bscan, cursor, N);
  dde_pass2_scatter<<<eb, 256, 0, stream>>>(h_id, t_id, r_id, f1n, g1n,
                                            F2_t, G2_h, cursor, se, E);

  int heb = (N * 36 + 255) / 256;
  build_he<<<heb, 256, 0, stream>>>(emb, nte, topic, f1n, g1n,
                                    F2_t, G2_h, P1t, P1h, He, N, nText);
  rel_cvt<<<(NR * 256 + 255) / 256, 256, 0, stream>>>(rel, relb, NR * 256);

  int ggrid = 4 * ((N + 255) / 256);
  dim3 agrid(2, (NR + 127) / 128);
  int edgeb = (E + 8 * EITER - 1) / (8 * EITER);
  for (int p = 0; p < 3; ++p) {
    int ns = (p == 2) ? 1 : 2;
    for (int k = 0; k < ns; ++k) {
      int s = p * 2 + k;
      sample_kernel<<<(267264 + 513 + 255) / 256, 256, 0, stream>>>(
          s, w1_mu, w1_rho, b1_mu, b1_rho, w2_mu, w2_rho, b2_mu, b2_rho,
          W1s, b1s, k ? w2s1 : w2s0, k ? b2s1 : b2s0, As, Asr);
      c_kernel<<<64, 256, 0, stream>>>(W1s, b1s, q, cvec);
      ar_mfma <<<agrid, 256, 0, stream>>>(relb, Asr, cvec, k ? Arc1 : Arc0, NR);
      gemm_mfma<<<ggrid, 512, 0, stream>>>(He, As, k ? U1 : U0, N);
    }
    int mode = (p == 0) ? 0 : ((p == 2) ? 2 : 1);
    edge2_kernel<<<edgeb, 256, 0, stream>>>(se, U0, U1, Arc0, Arc1,
                                            w2s0, w2s1, b2s0, b2s1,
                                            eacc, out, E, ns, mode);
  }
  (void)n_in; (void)out_size; (void)ws_size;
}

// Round 18
// 779.469 us; speedup vs baseline: 1.0809x; 1.0809x over previous
//
#include <hip/hip_runtime.h>
#include <hip/hip_bf16.h>

typedef __attribute__((ext_vector_type(8))) short short8;
typedef __attribute__((ext_vector_type(4))) float f32x4;
typedef unsigned long long u64;

#define GLOAD16(g, l) __builtin_amdgcn_global_load_lds( \
    (const __attribute__((address_space(1))) void*)(g), \
    (__attribute__((address_space(3))) void*)(l), 16, 0, 0)

#define F18 262144.0f            // 2^18 pass1 fixed-point scale
#define F18I (1.0f / 262144.0f)
#define F20 1048576.0f           // 2^20 pass2 fixed-point scale
#define F20I (1.0f / 1048576.0f)

__device__ __forceinline__ ushort f2bf(float v)
{
  __hip_bfloat16 b = __float2bfloat16(v);
  return *reinterpret_cast<ushort*>(&b);
}

// bijective XCD-chunk swizzle (m204): each of 8 XCDs gets a contiguous chunk
__device__ __forceinline__ int xcd_swz(int bid, int nwg)
{
  int q = nwg >> 3, rr = nwg & 7;
  int xcd = bid & 7, idx = bid >> 3;
  return (xcd < rr) ? xcd * (q + 1) + idx : rr * (q + 1) + (xcd - rr) * q + idx;
}

// ---------------------------------------------------------------------------
// Threefry2x32 (JAX partitionable semantics) + erfinv (XLA f32 polynomial)
// ---------------------------------------------------------------------------
#define TF_ROUND(r) { x0 += x1; x1 = ((x1<<(r))|(x1>>(32-(r)))); x1 ^= x0; }

__device__ __forceinline__ void tf2x32(unsigned k0, unsigned k1, unsigned x0, unsigned x1,
                                       unsigned &o0, unsigned &o1)
{
  unsigned ks2 = k0 ^ k1 ^ 0x1BD11BDAu;
  x0 += k0; x1 += k1;
  TF_ROUND(13) TF_ROUND(15) TF_ROUND(26) TF_ROUND(6)
  x0 += k1;  x1 += ks2 + 1u;
  TF_ROUND(17) TF_ROUND(29) TF_ROUND(16) TF_ROUND(24)
  x0 += ks2; x1 += k0 + 2u;
  TF_ROUND(13) TF_ROUND(15) TF_ROUND(26) TF_ROUND(6)
  x0 += k0;  x1 += k1 + 3u;
  TF_ROUND(17) TF_ROUND(29) TF_ROUND(16) TF_ROUND(24)
  x0 += k1;  x1 += ks2 + 4u;
  TF_ROUND(13) TF_ROUND(15) TF_ROUND(26) TF_ROUND(6)
  x0 += ks2; x1 += k0 + 5u;
  o0 = x0; o1 = x1;
}

__device__ __forceinline__ float erfinv_f(float x)
{
  float w = -log1pf(-x * x);
  float p;
  if (w < 5.0f) {
    w -= 2.5f;
    p = 2.81022636e-08f;
    p = fmaf(p, w, 3.43273939e-07f);
    p = fmaf(p, w, -3.5233877e-06f);
    p = fmaf(p, w, -4.39150654e-06f);
    p = fmaf(p, w, 0.00021858087f);
    p = fmaf(p, w, -0.00125372503f);
    p = fmaf(p, w, -0.00417768164f);
    p = fmaf(p, w, 0.246640727f);
    p = fmaf(p, w, 1.50140941f);
  } else {
    w = sqrtf(w) - 3.0f;
    p = -0.000200214257f;
    p = fmaf(p, w, 0.000100950558f);
    p = fmaf(p, w, 0.00134934322f);
    p = fmaf(p, w, -0.00367342844f);
    p = fmaf(p, w, 0.00573950773f);
    p = fmaf(p, w, -0.0076224613f);
    p = fmaf(p, w, 0.00943887047f);
    p = fmaf(p, w, 1.00167406f);
    p = fmaf(p, w, 2.83297682f);
  }
  return p * x;
}

__device__ __forceinline__ float rng_normal(unsigned b)
{
  float f = __uint_as_float((b >> 9) | 0x3f800000u) - 1.0f;  // [0,1)
  const float lo = -0.99999994f;
  float u = fmaxf(lo, f * 2.0f + lo);
  return 1.41421356f * erfinv_f(u);
}

__device__ __forceinline__ float softplusf(float x) { return log1pf(expf(x)); }

// ---------------------------------------------------------------------------
// DDE pass1 — packed u64 atomics [count:12][y:26][x:26] @2^18.
// P1h's count field doubles as the h-histogram for the edge sort.
// ---------------------------------------------------------------------------
__global__ void dde_pass1(const int* __restrict__ h, const int* __restrict__ t,
                          const float* __restrict__ topic,
                          u64* __restrict__ P1t, u64* __restrict__ P1h, int E)
{
  int e = blockIdx.x * blockDim.x + threadIdx.x;
  if (e >= E) return;
  int hh = h[e], tt = t[e];
  float2 th = *reinterpret_cast<const float2*>(&topic[hh * 2]);
  float2 tv = *reinterpret_cast<const float2*>(&topic[tt * 2]);
  u64 vt = (1ULL << 52) | ((u64)(unsigned)(th.y * F18 + 0.5f) << 26) | (unsigned)(th.x * F18 + 0.5f);
  u64 vh = (1ULL << 52) | ((u64)(unsigned)(tv.y * F18 + 0.5f) << 26) | (unsigned)(tv.x * F18 + 0.5f);
  atomicAdd(&P1t[tt], vt);
  atomicAdd(&P1h[hh], vh);
}

__global__ void dde_norm1(const u64* __restrict__ P1t, const u64* __restrict__ P1h,
                          float* __restrict__ f1n, float* __restrict__ g1n, int N)
{
  int n = blockIdx.x * blockDim.x + threadIdx.x;
  if (n >= N) return;
  u64 pt = P1t[n];
  float st = F18I / fmaxf((float)(unsigned)(pt >> 52), 1.0f);
  f1n[n*2+0] = (float)(unsigned)(pt & 0x3FFFFFFu) * st;
  f1n[n*2+1] = (float)(unsigned)((pt >> 26) & 0x3FFFFFFu) * st;
  u64 ph = P1h[n];
  float sh = F18I / fmaxf((float)(unsigned)(ph >> 52), 1.0f);
  g1n[n*2+0] = (float)(unsigned)(ph & 0x3FFFFFFu) * sh;
  g1n[n*2+1] = (float)(unsigned)((ph >> 26) & 0x3FFFFFFu) * sh;
}

// ---------------------------------------------------------------------------
// FUSED: DDE pass2 + counting-sort scatter — 2 atomics/edge.
// G2_h packs [count:12][y:26][x:26] @2^20 (max deg ~25 << 4096, no overflow);
// the returned count gives the scatter position: pos = cbase[hh] + count.
// ---------------------------------------------------------------------------
__global__ void dde_pass2_scatter(const int* __restrict__ h, const int* __restrict__ t,
                                  const int* __restrict__ r,
                                  const float* __restrict__ f1n, const float* __restrict__ g1n,
                                  u64* __restrict__ F2_t, u64* __restrict__ G2_h,
                                  const int* __restrict__ cbase, int4* __restrict__ se, int E)
{
  int e = blockIdx.x * blockDim.x + threadIdx.x;
  if (e >= E) return;
  int hh = h[e], tt = t[e];
  float2 fv = *reinterpret_cast<const float2*>(&f1n[hh * 2]);
  float2 gv = *reinterpret_cast<const float2*>(&g1n[tt * 2]);
  atomicAdd(&F2_t[tt], ((u64)(unsigned)(fv.y * F20 + 0.5f) << 32) | (unsigned)(fv.x * F20 + 0.5f));
  u64 old = atomicAdd(&G2_h[hh],
      (1ULL << 52) | ((u64)(unsigned)(gv.y * F20 + 0.5f) << 26) | (unsigned)(gv.x * F20 + 0.5f));
  int pos = cbase[hh] + (int)(unsigned)(old >> 52);
  se[pos] = make_int4(hh, tt, r[e], e);
}

// ---------------------------------------------------------------------------
// Edge counting sort scans: counts come from P1h[52:].
// ---------------------------------------------------------------------------
__global__ void scan1(const u64* __restrict__ P1h, int* __restrict__ bsum, int N)
{
  __shared__ int sh[256];
  int b = blockIdx.x, t = threadIdx.x;
  int base = b * 1024 + t * 4;
  int s = 0;
  #pragma unroll
  for (int i = 0; i < 4; ++i) if (base + i < N) s += (int)(unsigned)(P1h[base + i] >> 52);
  sh[t] = s;
  __syncthreads();
  for (int off = 128; off >= 1; off >>= 1) {
    if (t < off) sh[t] += sh[t + off];
    __syncthreads();
  }
  if (t == 0) bsum[b] = sh[0];
}

__global__ void scan2(const int* __restrict__ bsum, int* __restrict__ bscan, int NB)
{
  __shared__ int sh[256];
  int t = threadIdx.x;
  sh[t] = (t < NB) ? bsum[t] : 0;
  __syncthreads();
  if (t == 0) {
    int run = 0;
    for (int i = 0; i < NB; ++i) { int v = sh[i]; sh[i] = run; run += v; }
  }
  __syncthreads();
  if (t < NB) bscan[t] = sh[t];
}

__global__ void scan3(const u64* __restrict__ P1h, const int* __restrict__ bscan,
                      int* __restrict__ cursor, int N)
{
  __shared__ int sh[256];
  int b = blockIdx.x, t = threadIdx.x;
  int base = b * 1024 + t * 4;
  int c[4];
  #pragma unroll
  for (int i = 0; i < 4; ++i) c[i] = (base + i < N) ? (int)(unsigned)(P1h[base + i] >> 52) : 0;
  int mysum = c[0] + c[1] + c[2] + c[3];
  sh[t] = mysum;
  __syncthreads();
  for (int off = 1; off < 256; off <<= 1) {
    int u = (t >= off) ? sh[t - off] : 0;
    __syncthreads();
    sh[t] += u;
    __syncthreads();
  }
  int excl = sh[t] - mysum + bscan[b];
  #pragma unroll
  for (int i = 0; i < 4; ++i) {
    if (base + i < N) cursor[base + i] = excl;
    excl += c[i];
  }
}

// ---------------------------------------------------------------------------
// Entity feature matrix h_e : [N][288] bf16 — vectorized, norm2 fused.
// G2_h unpacks with the [count:12][y:26][x:26] layout.
// ---------------------------------------------------------------------------
__global__ void build_he(const float* __restrict__ emb, const float* __restrict__ nte,
                         const float* __restrict__ topic,
                         const float* __restrict__ f1, const float* __restrict__ g1,
                         const u64* __restrict__ F2_t, const u64* __restrict__ G2_h,
                         const u64* __restrict__ P1t, const u64* __restrict__ P1h,
                         __hip_bfloat16* __restrict__ He, int N, int nText)
{
  int idx = blockIdx.x * blockDim.x + threadIdx.x;
  if (idx >= N * 36) return;
  int n = idx / 36, j8 = idx - n * 36;
  ushort r[8];
  if (j8 < 32) {
    const float* src = (n < nText) ? &emb[(size_t)n * 256 + j8 * 8] : &nte[j8 * 8];
    float4 v0 = *reinterpret_cast<const float4*>(src);
    float4 v1 = *reinterpret_cast<const float4*>(src + 4);
    const float vv[8] = {v0.x, v0.y, v0.z, v0.w, v1.x, v1.y, v1.z, v1.w};
    #pragma unroll
    for (int i = 0; i < 8; ++i) r[i] = f2bf(vv[i]);
  } else if (j8 == 32) {
    float2 tp = *reinterpret_cast<const float2*>(&topic[n*2]);
    float2 a  = *reinterpret_cast<const float2*>(&f1[n*2]);
    float st = F20I / fmaxf((float)(unsigned)(P1t[n] >> 52), 1.0f);
    u64 f = F2_t[n];
    float f2x = (float)(unsigned)(f & 0xFFFFFFFFu) * st;
    float f2y = (float)(unsigned)(f >> 32) * st;
    float2 cq = *reinterpret_cast<const float2*>(&g1[n*2]);
    const float vv[8] = {tp.x, tp.y, a.x, a.y, f2x, f2y, cq.x, cq.y};
    #pragma unroll
    for (int i = 0; i < 8; ++i) r[i] = f2bf(vv[i]);
  } else if (j8 == 33) {
    float sh = F20I / fmaxf((float)(unsigned)(P1h[n] >> 52), 1.0f);
    u64 g = G2_h[n];
    r[0] = f2bf((float)(unsigned)(g & 0x3FFFFFFu) * sh);
    r[1] = f2bf((float)(unsigned)((g >> 26) & 0x3FFFFFFu) * sh);
    #pragma unroll
    for (int i = 2; i < 8; ++i) r[i] = 0;
  } else {
    #pragma unroll
    for (int i = 0; i < 8; ++i) r[i] = 0;
  }
  *reinterpret_cast<short8*>((ushort*)He + (size_t)n * 288 + j8 * 8) =
      *reinterpret_cast<const short8*>(r);
}

// rel -> bf16 (one-time)
__global__ void rel_cvt(const float* __restrict__ rel, __hip_bfloat16* __restrict__ relb, int n)
{
  int i = blockIdx.x * blockDim.x + threadIdx.x;
  if (i < n) relb[i] = __float2bfloat16(rel[i]);
}

// ---------------------------------------------------------------------------
// Bayesian weight sampling (JAX threefry, partitionable) + packing (verified)
// ---------------------------------------------------------------------------
__global__ void sample_kernel(int s,
                              const float* __restrict__ w1_mu, const float* __restrict__ w1_rho,
                              const float* __restrict__ b1_mu, const float* __restrict__ b1_rho,
                              const float* __restrict__ w2_mu, const float* __restrict__ w2_rho,
                              const float* __restrict__ b2_mu, const float* __restrict__ b2_rho,
                              float* __restrict__ W1s, float* __restrict__ b1s,
                              float* __restrict__ w2s, float* __restrict__ b2s,
                              __hip_bfloat16* __restrict__ As, __hip_bfloat16* __restrict__ Asr)
{
  const int W1N = 267264;   // 256*1044
  int tid = blockIdx.x * blockDim.x + threadIdx.x;
  unsigned F0, F1;
  tf2x32(0u, 42u, 0u, (unsigned)s, F0, F1);   // fold_in(key(42), s)

  if (tid < W1N) {
    unsigned k0, k1; tf2x32(F0, F1, 0u, 0u, k0, k1);              // sk0
    unsigned o0, o1; tf2x32(k0, k1, 0u, (unsigned)tid, o0, o1);
    float w = fmaf(rng_normal(o0 ^ o1), softplusf(w1_rho[tid]), w1_mu[tid]);
    W1s[tid] = w;
    int m = tid / 1044, j = tid - m * 1044;
    if (j >= 256 && j < 522)      As[m * 288 + (j - 256)]         = __float2bfloat16(w);
    else if (j >= 522 && j < 778) Asr[m * 256 + (j - 522)]        = __float2bfloat16(w);
    else if (j >= 778)            As[(256 + m) * 288 + (j - 778)] = __float2bfloat16(w);
  } else if (tid < W1N + 256) {
    int m = tid - W1N;
    unsigned k0, k1; tf2x32(F0, F1, 0u, 1u, k0, k1);              // sk1
    unsigned o0, o1; tf2x32(k0, k1, 0u, (unsigned)m, o0, o1);
    b1s[m] = fmaf(rng_normal(o0 ^ o1), softplusf(b1_rho[m]), b1_mu[m]);
  } else if (tid < W1N + 512) {
    int m = tid - (W1N + 256);
    unsigned k0, k1; tf2x32(F0, F1, 0u, 2u, k0, k1);              // sk2
    unsigned o0, o1; tf2x32(k0, k1, 0u, (unsigned)m, o0, o1);
    w2s[m] = fmaf(rng_normal(o0 ^ o1), softplusf(w2_rho[m]), w2_mu[m]);
  } else if (tid == W1N + 512) {
    unsigned k0, k1; tf2x32(F0, F1, 0u, 3u, k0, k1);              // sk3
    unsigned o0, o1; tf2x32(k0, k1, 0u, 0u, o0, o1);
    b2s[0] = fmaf(rng_normal(o0 ^ o1), softplusf(b2_rho[0]), b2_mu[0]);
  }
}

// c[k] = b1s[k] + sum_j W1s[k][j] * q[j]  — one wave per k, coalesced (f32)
__global__ void c_kernel(const float* __restrict__ W1s, const float* __restrict__ b1s,
                         const float* __restrict__ q, float* __restrict__ cvec)
{
  int k = blockIdx.x * 4 + (threadIdx.x >> 6);
  int lane = threadIdx.x & 63;
  float4 v  = *reinterpret_cast<const float4*>(&W1s[(size_t)k * 1044 + lane * 4]);
  float4 qv = *reinterpret_cast<const float4*>(&q[lane * 4]);
  float acc = v.x*qv.x + v.y*qv.y + v.z*qv.z + v.w*qv.w;
  #pragma unroll
  for (int off = 32; off >= 1; off >>= 1) acc += __shfl_down(acc, off, 64);
  if (lane == 0) cvec[k] = acc + b1s[k];
}

// ---------------------------------------------------------------------------
// Arc[r][k] = cvec[k] + sum_j rel[r][j]*W1[k][522+j] via MFMA. f32 out.
// ---------------------------------------------------------------------------
__global__ __launch_bounds__(256) void ar_mfma(const __hip_bfloat16* __restrict__ relb_,
                                               const __hip_bfloat16* __restrict__ Asr_,
                                               const float* __restrict__ cvec,
                                               float* __restrict__ Arc, int NRr)
{
  const int lane = threadIdx.x & 63;
  const int wid  = threadIdx.x >> 6;
  const int wr = wid >> 1, wc = wid & 1;
  const int r0 = blockIdx.y * 128 + wr * 64;
  const int k0 = blockIdx.x * 128 + wc * 64;
  const int lr = lane & 15, lk = (lane >> 4) * 8;
  const short* A = (const short*)relb_;
  const short* B = (const short*)Asr_;

  const short* pa[4];
  const short* pb[4];
  #pragma unroll
  for (int i = 0; i < 4; ++i) {
    int rr = r0 + i * 16 + lr; if (rr >= NRr) rr = NRr - 1;
    pa[i] = A + (size_t)rr * 256 + lk;
    pb[i] = B + (size_t)(k0 + i * 16 + lr) * 256 + lk;
  }
  f32x4 acc[4][4] = {};
  #pragma unroll
  for (int ks = 0; ks < 8; ++ks) {
    short8 a[4], b[4];
    #pragma unroll
    for (int i = 0; i < 4; ++i) a[i] = *reinterpret_cast<const short8*>(pa[i] + ks * 32);
    #pragma unroll
    for (int j = 0; j < 4; ++j) b[j] = *reinterpret_cast<const short8*>(pb[j] + ks * 32);
    #pragma unroll
    for (int i = 0; i < 4; ++i)
      #pragma unroll
      for (int j = 0; j < 4; ++j)
        acc[i][j] = __builtin_amdgcn_mfma_f32_16x16x32_bf16(a[i], b[j], acc[i][j], 0, 0, 0);
  }
  const int rg = (lane >> 4) * 4;
  #pragma unroll
  for (int i = 0; i < 4; ++i) {
    #pragma unroll
    for (int r_ = 0; r_ < 4; ++r_) {
      int r = r0 + i * 16 + rg + r_;
      if (r < NRr) {
        #pragma unroll
        for (int j = 0; j < 4; ++j) {
          int k = k0 + j * 16 + lr;
          Arc[(size_t)r * 256 + k] = acc[i][j][r_] + cvec[k];
        }
      }
    }
  }
}

// ---------------------------------------------------------------------------
// MFMA GEMM v4 (verified): 256n x 128m tile, BK=32, 8 waves, dbuf LDS via
// global_load_lds w16, 4-way-max XOR swizzle, XCD-chunk-swizzled 1-D grid.
// ---------------------------------------------------------------------------
__global__ __launch_bounds__(512) void gemm_mfma(const __hip_bfloat16* __restrict__ Heb,
                                                 const __hip_bfloat16* __restrict__ Asb,
                                                 __hip_bfloat16* __restrict__ U, int nEnt)
{
  __shared__ short lA[2][8192];
  __shared__ short lB[2][4096];

  const int tid  = threadIdx.x;
  const int lane = tid & 63;
  const int wid  = tid >> 6;
  const int wr   = wid >> 1;
  const int wc   = wid & 1;
  const int swzb = xcd_swz(blockIdx.x, gridDim.x);
  const int m0   = (swzb & 3) * 128;
  const int n0   = (swzb >> 2) * 256;
  const short* He = (const short*)Heb;
  const short* As = (const short*)Asb;

  const int lr  = lane & 15;
  const int kb  = (lane >> 4) * 16;
  const int swz = (lane & 3) << 4;

  const int g0row = tid >> 2, g0c = tid & 3;
  const int g1row = g0row + 128;
  const int maxA = nEnt - n0 - 1;
  const int a0r = g0row <= maxA ? g0row : maxA;
  const int a1r = g1row <= maxA ? g1row : maxA;
  const size_t aoff0 = (size_t)a0r * 288 + (g0c ^ (g0row & 3)) * 8;
  const size_t aoff1 = (size_t)a1r * 288 + (g0c ^ (g1row & 3)) * 8;
  const size_t boff0 = (size_t)g0row * 288 + (g0c ^ (g0row & 3)) * 8;
  const short* gA = He + (size_t)n0 * 288;
  const short* gB = As + (size_t)m0 * 288;

  #define STAGE(buf, k0)                                              \
    { GLOAD16(gA + (k0) + aoff0, (char*)lA[buf] + tid * 16);          \
      GLOAD16(gA + (k0) + aoff1, (char*)lA[buf] + tid * 16 + 8192);   \
      GLOAD16(gB + (k0) + boff0, (char*)lB[buf] + tid * 16); }

  f32x4 acc[4][4] = {};

  STAGE(0, 0)
  __syncthreads();

  #pragma unroll 1
  for (int ks = 0; ks < 9; ++ks) {
    const int cur = ks & 1;
    if (ks < 8) STAGE(cur ^ 1, (ks + 1) * 32)

    short8 a[4], b[4];
    #pragma unroll
    for (int i = 0; i < 4; ++i) {
      int rowA = wr * 64 + i * 16 + lr;
      a[i] = *reinterpret_cast<const short8*>((const char*)lA[cur] + rowA * 64 + (kb ^ swz));
      int rowB = wc * 64 + i * 16 + lr;
      b[i] = *reinterpret_cast<const short8*>((const char*)lB[cur] + rowB * 64 + (kb ^ swz));
    }
    #pragma unroll
    for (int i = 0; i < 4; ++i)
      #pragma unroll
      for (int j = 0; j < 4; ++j)
        acc[i][j] = __builtin_amdgcn_mfma_f32_16x16x32_bf16(a[i], b[j], acc[i][j], 0, 0, 0);

    __syncthreads();
  }
  #undef STAGE

  const int rg = (lane >> 4) * 4;
  #pragma unroll
  for (int i = 0; i < 4; ++i) {
    #pragma unroll
    for (int r = 0; r < 4; ++r) {
      int n = n0 + wr * 64 + i * 16 + rg + r;
      if (n < nEnt) {
        #pragma unroll
        for (int j = 0; j < 4; ++j)
          U[(size_t)n * 512 + m0 + wc * 64 + j * 16 + lr] = __float2bfloat16(acc[i][j][r]);
      }
    }
  }
}

// ---------------------------------------------------------------------------
// Edge pass (R15-proven): grid-stride x4 over h-sorted edges, w2/b2 hoisted,
// XCD-chunk-swizzled blocks.
// ---------------------------------------------------------------------------
#define EITER 4
__global__ __launch_bounds__(256) void edge_kernel(const int4* __restrict__ se,
                                                   const __hip_bfloat16* __restrict__ U,
                                                   const float* __restrict__ Arc,
                                                   const float* __restrict__ w2s,
                                                   const float* __restrict__ b2s,
                                                   float* __restrict__ acc,
                                                   float* __restrict__ out, int E, int mode)
{
  int blk = xcd_swz(blockIdx.x, gridDim.x);
  int g = threadIdx.x >> 5;
  int l = threadIdx.x & 31;
  int base = blk * (8 * EITER) + g * EITER;
  const ushort* Ub = (const ushort*)U;

  float4 w0 = *reinterpret_cast<const float4*>(&w2s[l * 8]);
  float4 w1 = *reinterpret_cast<const float4*>(&w2s[l * 8 + 4]);
  const float ww[8] = {w0.x, w0.y, w0.z, w0.w, w1.x, w1.y, w1.z, w1.w};
  float b2 = b2s[0];

  #pragma unroll 1
  for (int it = 0; it < EITER; ++it) {
    int e = base + it;
    if (e >= E) break;
    int4 ed = se[e];

    uint4 uhv = *reinterpret_cast<const uint4*>(Ub + (size_t)ed.x * 512 + l * 8);
    uint4 utv = *reinterpret_cast<const uint4*>(Ub + (size_t)ed.y * 512 + 256 + l * 8);
    float4 a0 = *reinterpret_cast<const float4*>(&Arc[(size_t)ed.z * 256 + l * 8]);
    float4 a1 = *reinterpret_cast<const float4*>(&Arc[(size_t)ed.z * 256 + l * 8 + 4]);

    float uh[8], ut[8];
    uh[0] = __uint_as_float(uhv.x << 16); uh[1] = __uint_as_float(uhv.x & 0xFFFF0000u);
    uh[2] = __uint_as_float(uhv.y << 16); uh[3] = __uint_as_float(uhv.y & 0xFFFF0000u);
    uh[4] = __uint_as_float(uhv.z << 16); uh[5] = __uint_as_float(uhv.z & 0xFFFF0000u);
    uh[6] = __uint_as_float(uhv.w << 16); uh[7] = __uint_as_float(uhv.w & 0xFFFF0000u);
    ut[0] = __uint_as_float(utv.x << 16); ut[1] = __uint_as_float(utv.x & 0xFFFF0000u);
    ut[2] = __uint_as_float(utv.y << 16); ut[3] = __uint_as_float(utv.y & 0xFFFF0000u);
    ut[4] = __uint_as_float(utv.z << 16); ut[5] = __uint_as_float(utv.z & 0xFFFF0000u);
    ut[6] = __uint_as_float(utv.w << 16); ut[7] = __uint_as_float(utv.w & 0xFFFF0000u);

    const float aa[8] = {a0.x, a0.y, a0.z, a0.w, a1.x, a1.y, a1.z, a1.w};

    float sum = 0.0f;
    #pragma unroll
    for (int i = 0; i < 8; ++i)
      sum += ww[i] * fmaxf(aa[i] + uh[i] + ut[i], 0.0f);

    #pragma unroll
    for (int off = 16; off >= 1; off >>= 1) sum += __shfl_down(sum, off, 32);

    if (l == 0) {
      float v = sum + b2;
      if (mode == 0)      acc[e] = v;
      else if (mode == 1) acc[e] += v;
      else                out[ed.w] = (acc[e] + v) * 0.2f;
    }
  }
}

// ---------------------------------------------------------------------------
// Host launcher
// ---------------------------------------------------------------------------
extern "C" void kernel_launch(void* const* d_in, const int* in_sizes, int n_in,
                              void* d_out, int out_size, void* d_ws, size_t ws_size,
                              hipStream_t stream)
{
  const int*   h_id  = (const int*)  d_in[0];
  const int*   r_id  = (const int*)  d_in[1];
  const int*   t_id  = (const int*)  d_in[2];
  const float* q     = (const float*)d_in[3];
  const float* emb   = (const float*)d_in[4];
  const float* rel   = (const float*)d_in[6];
  const float* topic = (const float*)d_in[7];
  const float* nte   = (const float*)d_in[8];
  const float* w1_mu = (const float*)d_in[9];
  const float* w1_rho= (const float*)d_in[10];
  const float* b1_mu = (const float*)d_in[11];
  const float* b1_rho= (const float*)d_in[12];
  const float* w2_mu = (const float*)d_in[13];
  const float* w2_rho= (const float*)d_in[14];
  const float* b2_mu = (const float*)d_in[15];
  const float* b2_rho= (const float*)d_in[16];

  const int E     = in_sizes[0];
  const int nText = in_sizes[4] / 256;
  const int N     = in_sizes[7] / 2;
  const int NR    = in_sizes[6] / 256;
  float* out = (float*)d_out;

  char* ws = (char*)d_ws;
  size_t off = 0;
  auto alloc = [&](size_t bytes) -> void* {
    void* p = (void*)(ws + off);
    off += (bytes + 255) & ~(size_t)255;
    return p;
  };
  __hip_bfloat16* He  = (__hip_bfloat16*)alloc((size_t)N * 288 * 2);
  __hip_bfloat16* U   = (__hip_bfloat16*)alloc((size_t)N * 512 * 2);
  __hip_bfloat16* Asr = (__hip_bfloat16*)alloc(256 * 256 * 2);
  __hip_bfloat16* relb= (__hip_bfloat16*)alloc((size_t)NR * 256 * 2);
  float* Arc  = (float*)alloc((size_t)NR * 256 * 4);
  float* W1s  = (float*)alloc(267264 * 4);
  float* b1s  = (float*)alloc(256 * 4);
  float* w2s  = (float*)alloc(256 * 4);
  float* b2s  = (float*)alloc(64 * 4);
  float* cvec = (float*)alloc(256 * 4);
  float* f1n  = (float*)alloc((size_t)2 * N * 4);
  float* g1n  = (float*)alloc((size_t)2 * N * 4);
  float* eacc = (float*)alloc((size_t)E * 4);
  int4*  se   = (int4*)alloc((size_t)E * 16);
  const int NB = (N + 1023) / 1024;
  int* cursor = (int*)alloc((size_t)NB * 1024 * 4);
  int* bsum   = (int*)alloc(256 * 4);
  int* bscan  = (int*)alloc(256 * 4);
  // zero-init region: As pad cols + packed DDE accumulators
  __hip_bfloat16* As = (__hip_bfloat16*)alloc(512 * 288 * 2);
  u64* P1t  = (u64*)alloc((size_t)N * 8);
  u64* P1h  = (u64*)alloc((size_t)N * 8);
  u64* F2_t = (u64*)alloc((size_t)N * 8);
  u64* G2_h = (u64*)alloc((size_t)N * 8);

  size_t zero_bytes = (size_t)((char*)(G2_h + N) - (char*)As);
  hipMemsetAsync(As, 0, zero_bytes, stream);

  int eb = (E + 255) / 256;
  int nb = (N + 255) / 256;
  dde_pass1<<<eb, 256, 0, stream>>>(h_id, t_id, topic, P1t, P1h, E);
  dde_norm1<<<nb, 256, 0, stream>>>(P1t, P1h, f1n, g1n, N);

  // counting-sort base offsets (from P1h high bits), then fused pass2+scatter
  scan1<<<NB, 256, 0, stream>>>(P1h, bsum, N);
  scan2<<<1, 256, 0, stream>>>(bsum, bscan, NB);
  scan3<<<NB, 256, 0, stream>>>(P1h, bscan, cursor, N);
  dde_pass2_scatter<<<eb, 256, 0, stream>>>(h_id, t_id, r_id, f1n, g1n,
                                            F2_t, G2_h, cursor, se, E);

  int heb = (N * 36 + 255) / 256;
  build_he<<<heb, 256, 0, stream>>>(emb, nte, topic, f1n, g1n,
                                    F2_t, G2_h, P1t, P1h, He, N, nText);
  rel_cvt<<<(NR * 256 + 255) / 256, 256, 0, stream>>>(rel, relb, NR * 256);

  int ggrid = 4 * ((N + 255) / 256);
  dim3 agrid(2, (NR + 127) / 128);
  int edgeb = (E + 8 * EITER - 1) / (8 * EITER);
  for (int s = 0; s < 5; ++s) {
    sample_kernel<<<(267264 + 513 + 255) / 256, 256, 0, stream>>>(
        s, w1_mu, w1_rho, b1_mu, b1_rho, w2_mu, w2_rho, b2_mu, b2_rho,
        W1s, b1s, w2s, b2s, As, Asr);
    c_kernel<<<64, 256, 0, stream>>>(W1s, b1s, q, cvec);
    ar_mfma <<<agrid, 256, 0, stream>>>(relb, Asr, cvec, Arc, NR);
    gemm_mfma<<<ggrid, 512, 0, stream>>>(He, As, U, N);
    int mode = (s == 0) ? 0 : ((s == 4) ? 2 : 1);
    edge_kernel<<<edgeb, 256, 0, stream>>>(se, U, Arc, w2s, b2s,
                                           eacc, out, E, mode);
  }
  (void)n_in; (void)out_size; (void)ws_size;
}